// Round 6
// baseline (114.298 us; speedup 1.0000x reference)
//
#include <hip/hip_runtime.h>
#include <math.h>

// Problem geometry
#define MTOT  16384      // B*L
#define DM    1024
#define HIDN  128
#define HNB   256
#define NBAT  4
#define CL    16         // rows per k_mega block == scan chunk
#define NBLK  (MTOT/CL)  // 1024 blocks / chunks
#define CPB   256        // chunks per batch (4096/16)

typedef _Float16 v8h __attribute__((ext_vector_type(8)));
typedef float    v4f __attribute__((ext_vector_type(4)));
#define MFMA16(a,b,c) __builtin_amdgcn_mfma_f32_16x16x32_f16((a),(b),(c),0,0,0)

// Weight blobs (in out1 region; overwritten by k_apply_fill at the end):
//  [0,655360):      W1 k-tiles kt=0..31, 20480 B: {W1h[col=128][40 fp16] | W1l}
//  [655360,819200): W2 k-tiles ks=0..3, 40960 B: {W2h[col=256][40] | W2l}
#define W1BLOB_TILE 20480
#define W2BLOB_BASE 655360
#define W2BLOB_TILE 40960

// ---------------------------------------------------------------------------
// K0: convert+transpose+pad weights into fp16 split blobs (unchanged R4/R5).
//     Xh = fp16(x); Xl = fp16((x - Xh) * 4096)
// ---------------------------------------------------------------------------
__global__ __launch_bounds__(256) void k_prep(
    const float* __restrict__ W1,   // [1024][128]
    const float* __restrict__ W2,   // [128][256]
    char* __restrict__ blobs)
{
    __shared__ float lds[32][260];
    const int t = threadIdx.x, blk = blockIdx.x;
    if (blk < 32) {
        const int k0 = blk * 32;
        #pragma unroll
        for (int i = 0; i < 4; ++i) {
            int j = t + i * 256;
            int k = j >> 5, n4 = (j & 31) << 2;
            *(float4*)&lds[k][n4] = *(const float4*)&W1[(size_t)(k0 + k) * HIDN + n4];
        }
        __syncthreads();
        const int n = t >> 1, kh = t & 1;
        union { _Float16 h[16]; int2 v[4]; } uh, ul;
        #pragma unroll
        for (int kk = 0; kk < 16; ++kk) {
            float v = lds[kh * 16 + kk][n];
            _Float16 hh = (_Float16)v;
            uh.h[kk] = hh;
            ul.h[kk] = (_Float16)((v - (float)hh) * 4096.f);
        }
        char* bh = blobs + blk * W1BLOB_TILE + n * 80 + kh * 32;
        #pragma unroll
        for (int i = 0; i < 4; ++i) {
            *(int2*)(bh + i * 8)         = uh.v[i];
            *(int2*)(bh + 10240 + i * 8) = ul.v[i];
        }
        if (kh == 1) {
            int2 z; z.x = 0; z.y = 0;
            char* ph = blobs + blk * W1BLOB_TILE + n * 80 + 64;
            *(int2*)(ph) = z; *(int2*)(ph + 8) = z;
            *(int2*)(ph + 10240) = z; *(int2*)(ph + 10240 + 8) = z;
        }
    } else {
        const int ks = blk - 32, k0 = ks * 32;
        #pragma unroll
        for (int i = 0; i < 8; ++i) {
            int j = t + i * 256;
            int k = j >> 6, n4 = (j & 63) << 2;
            *(float4*)&lds[k][n4] = *(const float4*)&W2[(size_t)(k0 + k) * HNB + n4];
        }
        __syncthreads();
        const int n = t;
        union { _Float16 h[40]; int2 v[10]; } uh, ul;
        #pragma unroll
        for (int kk = 0; kk < 32; ++kk) {
            float v = lds[kk][n];
            _Float16 hh = (_Float16)v;
            uh.h[kk] = hh;
            ul.h[kk] = (_Float16)((v - (float)hh) * 4096.f);
        }
        #pragma unroll
        for (int kk = 32; kk < 40; ++kk) { uh.h[kk] = (_Float16)0.f; ul.h[kk] = (_Float16)0.f; }
        char* bh = blobs + W2BLOB_BASE + ks * W2BLOB_TILE + n * 80;
        #pragma unroll
        for (int i = 0; i < 10; ++i) {
            *(int2*)(bh + i * 8)         = uh.v[i];
            *(int2*)(bh + 20480 + i * 8) = ul.v[i];
        }
    }
}

// ---------------------------------------------------------------------------
// K1: mega. One block = 16 rows = one scan chunk. 512 threads (8 waves),
// grid 1024. GEMM1 zero-LDS with distance-4 register prefetch rings (A from
// HBM, W1 from L2 blob; each wave owns a distinct 16-col W strip -> no
// duplicate W reads). theta prefetched to regs across GEMM2. 3 barriers.
// ---------------------------------------------------------------------------
__global__ __launch_bounds__(512, 4) void k_mega(
    const float* __restrict__ A,      // content [16384][1024]
    const float* __restrict__ theta,  // [16384][256]
    const float* __restrict__ b1, const float* __restrict__ b2,
    const float* __restrict__ logPi, const float* __restrict__ logR,
    const char* __restrict__ blobs,
    float* __restrict__ out0,         // S
    float* __restrict__ out2,         // K fill
    float* __restrict__ carry)        // out3: slot blk*4096 + c
{
    __shared__ __attribute__((aligned(16))) char smem[33280];
    // phase A: Hh @0 (4352 B), Hl @4352 (4352 B)
    // phase B: u[16][260] f32 @0 (16640), theta[16][260] f32 @16640

    const int tid  = threadIdx.x;
    const int blk  = blockIdx.x;
    const int m0   = blk * CL;
    const int lane = tid & 63;
    const int np   = tid >> 6;      // wave id 0..7
    const int ln15 = lane & 15;
    const int q    = lane >> 4;

    // ---------------- GEMM1: out 16x128, K=1024, per wave 16 cols ----------
    const float* arow = A + (size_t)(m0 + ln15) * DM + q * 8;
    const char*  w1p  = blobs + (16 * np + ln15) * 80 + q * 16;

    v4f acc1 = (v4f){0.f, 0.f, 0.f, 0.f};
    v4f acc2 = (v4f){0.f, 0.f, 0.f, 0.f};

    // distance-4 prefetch rings (statically indexed after unroll)
    float4 pa0[4], pa1[4];
    v8h pwh[4], pwl[4];
    #pragma unroll
    for (int j = 0; j < 4; ++j) {
        pa0[j] = *(const float4*)(arow + j * 32);
        pa1[j] = *(const float4*)(arow + j * 32 + 4);
        pwh[j] = *(const v8h*)(w1p + j * W1BLOB_TILE);
        pwl[j] = *(const v8h*)(w1p + j * W1BLOB_TILE + 10240);
    }

    for (int it = 0; it < 8; ++it) {
        #pragma unroll
        for (int j = 0; j < 4; ++j) {
            float4 ca0 = pa0[j], ca1 = pa1[j];
            v8h cwh = pwh[j], cwl = pwl[j];
            if (it < 7) {                         // prefetch k-step +4
                const int kn = (it + 1) * 4 + j;
                pa0[j] = *(const float4*)(arow + kn * 32);
                pa1[j] = *(const float4*)(arow + kn * 32 + 4);
                pwh[j] = *(const v8h*)(w1p + kn * W1BLOB_TILE);
                pwl[j] = *(const v8h*)(w1p + kn * W1BLOB_TILE + 10240);
            }
            float av[8] = {ca0.x, ca0.y, ca0.z, ca0.w, ca1.x, ca1.y, ca1.z, ca1.w};
            v8h ah, al;
            #pragma unroll
            for (int e = 0; e < 8; ++e) {
                _Float16 hh = (_Float16)av[e];
                ah[e] = hh;
                al[e] = (_Float16)((av[e] - (float)hh) * 4096.f);
            }
            acc1 = MFMA16(ah, cwh, acc1);
            acc2 = MFMA16(ah, cwl, acc2);
            acc2 = MFMA16(al, cwh, acc2);
        }
    }

    // ---------------- theta prefetch (in flight across GELU+GEMM2) --------
    float thv[2][4];
    #pragma unroll
    for (int ni = 0; ni < 2; ++ni)
        #pragma unroll
        for (int r = 0; r < 4; ++r)
            thv[ni][r] = theta[(size_t)(m0 + 4 * q + r) * HNB + 32 * np + 16 * ni + ln15];

    // ---------------- GELU -> H split into LDS ----------------
    {
        const int col = 16 * np + ln15;
        const float bv = b1[col];
        #pragma unroll
        for (int r = 0; r < 4; ++r) {
            float y = acc1[r] + acc2[r] * (1.f / 4096.f) + bv;
            float h = 0.5f * y * (1.f + erff(y * 0.70710678118654752f));
            _Float16 hh = (_Float16)h;
            _Float16 hl = (_Float16)((h - (float)hh) * 4096.f);
            const int row = 4 * q + r;
            *(_Float16*)(smem + row * 272 + col * 2)        = hh;
            *(_Float16*)(smem + 4352 + row * 272 + col * 2) = hl;
        }
    }
    __syncthreads();

    // ---------------- GEMM2: out 16x256, K=128, per wave 32 cols ----------
    v4f c1[2], c2[2];
    #pragma unroll
    for (int i = 0; i < 2; ++i) {
        c1[i] = (v4f){0.f, 0.f, 0.f, 0.f};
        c2[i] = (v4f){0.f, 0.f, 0.f, 0.f};
    }
    const char* hbase = smem + ln15 * 272 + q * 16;
    const char* w2p   = blobs + W2BLOB_BASE + (32 * np + ln15) * 80 + q * 16;

    #pragma unroll
    for (int ks = 0; ks < 4; ++ks) {
        v8h hh = *(const v8h*)(hbase + ks * 64);
        v8h hl = *(const v8h*)(hbase + 4352 + ks * 64);
        #pragma unroll
        for (int ni = 0; ni < 2; ++ni) {
            const char* wp = w2p + ks * W2BLOB_TILE + ni * 1280;
            v8h w2h = *(const v8h*)(wp);
            v8h w2l = *(const v8h*)(wp + 20480);
            c1[ni] = MFMA16(hh, w2h, c1[ni]);
            c2[ni] = MFMA16(hh, w2l, c2[ni]);
            c2[ni] = MFMA16(hl, w2h, c2[ni]);
        }
    }
    __syncthreads();   // H dead; smem becomes u + theta

    // ---------------- u-transform -> LDS; theta regs -> LDS ----------------
    #pragma unroll
    for (int ni = 0; ni < 2; ++ni) {
        const int col = 32 * np + 16 * ni + ln15;
        const float Pi = expf(logPi[col]);
        const float Rr = expf(logR[col]);
        const float Kv = Pi / fmaxf(Pi + Rr, 1e-8f);
        const float bv = b2[col];
        #pragma unroll
        for (int r = 0; r < 4; ++r) {
            const int row = 4 * q + r;
            float y2 = c1[ni][r] + c2[ni][r] * (1.f / 4096.f) + bv;
            float z  = 3.14159265358979323846f * tanhf(y2);
            float diff = z - thv[ni][r];
            float kq = rintf(diff * 0.15915494309189533577f);
            float nu = (float)((double)diff - (double)kq * 6.283185307179586476925286766559);
            *(float*)(smem + row * 1040 + col * 4)         = Kv * nu;
            *(float*)(smem + 16640 + row * 1040 + col * 4) = thv[ni][r];
        }
    }
    __syncthreads();

    // ---------------- in-block scan (16 rows); S, K-fill, carry ------------
    if (tid < 256) {
        const int c = tid;
        const float Pi = expf(logPi[c]);
        const float Rr = expf(logR[c]);
        const float Kc = Pi / fmaxf(Pi + Rr, 1e-8f);
        const float alpha = 1.f - Kc;
        float d = 0.f;
        float sv[CL];
        #pragma unroll
        for (int i = 0; i < CL; ++i) {
            d = fmaf(alpha, d, *(const float*)(smem + i * 1040 + c * 4));
            sv[i] = *(const float*)(smem + 16640 + i * 1040 + c * 4) + d;
        }
        #pragma unroll
        for (int i = 0; i < CL; ++i) {
            size_t idx = (size_t)(m0 + i) * HNB + c;
            out0[idx] = sv[i];
            out2[idx] = Kc;
        }
        carry[(size_t)blk * 4096 + c] = d;
    }
}

// ---------------------------------------------------------------------------
// K2: exclusive scan of chunk carries (factor alpha^16), per batch.
//     Writes incoming D into each chunk's own out3 region (slot base+c).
// ---------------------------------------------------------------------------
__global__ __launch_bounds__(256) void k_cscan(
    const float* __restrict__ logPi,
    const float* __restrict__ logR,
    float* __restrict__ carry)
{
    const int c = threadIdx.x;
    const int b = blockIdx.x;
    const float Pi = expf(logPi[c]);
    const float Rr = expf(logR[c]);
    const float alpha = 1.f - Pi / fmaxf(Pi + Rr, 1e-8f);
    float A16 = alpha;
    #pragma unroll
    for (int i = 0; i < 4; ++i) A16 = A16 * A16;   // alpha^16
    float D = 0.f;
    for (int batch = 0; batch < CPB / 16; ++batch) {
        float a[16];
        #pragma unroll
        for (int j = 0; j < 16; ++j)
            a[j] = carry[(size_t)(b * CPB + batch * 16 + j) * 4096 + c];
        #pragma unroll
        for (int j = 0; j < 16; ++j) {
            carry[(size_t)(b * CPB + batch * 16 + j) * 4096 + c] = D;
            D = fmaf(A16, D, a[j]);
        }
    }
}

// ---------------------------------------------------------------------------
// K3: out0 += alpha^(i+1)*D; fill Pi (out1), R (out3).
//     grid 1024 = one block per chunk; D read-before-fill from own region.
// ---------------------------------------------------------------------------
__global__ __launch_bounds__(256) void k_apply_fill(
    const float* __restrict__ logPi,
    const float* __restrict__ logR,
    float* __restrict__ out0, float* __restrict__ out1,
    float* __restrict__ out3)
{
    const int blk = blockIdx.x;
    const int c = threadIdx.x;
    const float Pi = expf(logPi[c]);
    const float Rr = expf(logR[c]);
    const float Kc = Pi / fmaxf(Pi + Rr, 1e-8f);
    const float alpha = 1.f - Kc;
    const size_t base = (size_t)blk * 4096 + c;
    float D = out3[base];          // incoming carry (this block's own region)
    float w = alpha * D;
    #pragma unroll 4
    for (int i = 0; i < CL; ++i) {
        size_t idx = base + (size_t)i * 256;
        out0[idx] += w;
        out1[idx] = Pi;
        out3[idx] = Rr;
        w *= alpha;
    }
}

extern "C" void kernel_launch(void* const* d_in, const int* in_sizes, int n_in,
                              void* d_out, int out_size, void* d_ws, size_t ws_size,
                              hipStream_t stream) {
    const float* theta   = (const float*)d_in[0];
    const float* content = (const float*)d_in[1];
    const float* W1      = (const float*)d_in[2];
    const float* b1      = (const float*)d_in[3];
    const float* W2      = (const float*)d_in[4];
    const float* b2      = (const float*)d_in[5];
    const float* logPi   = (const float*)d_in[6];
    const float* logR    = (const float*)d_in[7];

    float* out  = (float*)d_out;
    float* out0 = out;
    float* out1 = out + (size_t)MTOT * HNB;
    float* out2 = out + (size_t)2 * MTOT * HNB;
    float* out3 = out + (size_t)3 * MTOT * HNB;
    char*  blobs = (char*)out1;   // weight blobs until k_apply_fill fills out1

    hipLaunchKernelGGL(k_prep, dim3(36), dim3(256), 0, stream, W1, W2, blobs);
    hipLaunchKernelGGL(k_mega, dim3(NBLK), dim3(512), 0, stream,
                       content, theta, b1, b2, logPi, logR, blobs,
                       out0, out2, out3);
    hipLaunchKernelGGL(k_cscan, dim3(NBAT), dim3(256), 0, stream,
                       logPi, logR, out3);
    hipLaunchKernelGGL(k_apply_fill, dim3(NBLK), dim3(256), 0, stream,
                       logPi, logR, out0, out1, out3);
}

// Round 7
// 65.420 us; speedup vs baseline: 1.7471x; 1.7471x over previous
//
#include <hip/hip_runtime.h>
#include <math.h>

// Problem geometry
#define MTOT  16384      // B*L
#define DM    1024
#define HIDN  128
#define HNB   256
#define NBAT  4
#define CLK   32         // rows per k_mega block == scan chunk
#define NBLK  512        // MTOT/CLK
#define CPB   128        // chunks per batch (4096/32)

typedef _Float16 v8h __attribute__((ext_vector_type(8)));
typedef float    v4f __attribute__((ext_vector_type(4)));
#define MFMA16(a,b,c) __builtin_amdgcn_mfma_f32_16x16x32_f16((a),(b),(c),0,0,0)

// Weight blobs (in out1 region; overwritten by k_apply_fill at the end):
//  [0,655360):      W1 k-tiles kt=0..31, 20480 B: {W1h[col=128][40 fp16] | W1l}
//  [655360,819200): W2 k-tiles ks=0..3, 40960 B: {W2h[col=256][40] | W2l}
#define W1BLOB_TILE 20480
#define W2BLOB_BASE 655360
#define W2BLOB_TILE 40960

// Barrier that drains LDS ops only — global prefetches stay in flight (T3/T4).
#define BAR_LGKM() do { \
    asm volatile("s_waitcnt lgkmcnt(0)" ::: "memory"); \
    __builtin_amdgcn_s_barrier(); \
    __builtin_amdgcn_sched_barrier(0); \
} while (0)

// ---------------------------------------------------------------------------
// K0: convert+transpose+pad weights into fp16 split blobs (unchanged).
//     Xh = fp16(x); Xl = fp16((x - Xh) * 4096)
// ---------------------------------------------------------------------------
__global__ __launch_bounds__(256) void k_prep(
    const float* __restrict__ W1,   // [1024][128]
    const float* __restrict__ W2,   // [128][256]
    char* __restrict__ blobs)
{
    __shared__ float lds[32][260];
    const int t = threadIdx.x, blk = blockIdx.x;
    if (blk < 32) {
        const int k0 = blk * 32;
        #pragma unroll
        for (int i = 0; i < 4; ++i) {
            int j = t + i * 256;
            int k = j >> 5, n4 = (j & 31) << 2;
            *(float4*)&lds[k][n4] = *(const float4*)&W1[(size_t)(k0 + k) * HIDN + n4];
        }
        __syncthreads();
        const int n = t >> 1, kh = t & 1;
        union { _Float16 h[16]; int2 v[4]; } uh, ul;
        #pragma unroll
        for (int kk = 0; kk < 16; ++kk) {
            float v = lds[kh * 16 + kk][n];
            _Float16 hh = (_Float16)v;
            uh.h[kk] = hh;
            ul.h[kk] = (_Float16)((v - (float)hh) * 4096.f);
        }
        char* bh = blobs + blk * W1BLOB_TILE + n * 80 + kh * 32;
        #pragma unroll
        for (int i = 0; i < 4; ++i) {
            *(int2*)(bh + i * 8)         = uh.v[i];
            *(int2*)(bh + 10240 + i * 8) = ul.v[i];
        }
        if (kh == 1) {
            int2 z; z.x = 0; z.y = 0;
            char* ph = blobs + blk * W1BLOB_TILE + n * 80 + 64;
            *(int2*)(ph) = z; *(int2*)(ph + 8) = z;
            *(int2*)(ph + 10240) = z; *(int2*)(ph + 10240 + 8) = z;
        }
    } else {
        const int ks = blk - 32, k0 = ks * 32;
        #pragma unroll
        for (int i = 0; i < 8; ++i) {
            int j = t + i * 256;
            int k = j >> 6, n4 = (j & 63) << 2;
            *(float4*)&lds[k][n4] = *(const float4*)&W2[(size_t)(k0 + k) * HNB + n4];
        }
        __syncthreads();
        const int n = t;
        union { _Float16 h[40]; int2 v[10]; } uh, ul;
        #pragma unroll
        for (int kk = 0; kk < 32; ++kk) {
            float v = lds[kk][n];
            _Float16 hh = (_Float16)v;
            uh.h[kk] = hh;
            ul.h[kk] = (_Float16)((v - (float)hh) * 4096.f);
        }
        #pragma unroll
        for (int kk = 32; kk < 40; ++kk) { uh.h[kk] = (_Float16)0.f; ul.h[kk] = (_Float16)0.f; }
        char* bh = blobs + W2BLOB_BASE + ks * W2BLOB_TILE + n * 80;
        #pragma unroll
        for (int i = 0; i < 10; ++i) {
            *(int2*)(bh + i * 8)         = uh.v[i];
            *(int2*)(bh + 20480 + i * 8) = ul.v[i];
        }
    }
}

// ---------------------------------------------------------------------------
// K1: mega. One block = 32 rows = one scan chunk. 512 threads (8 waves =
// 2M x 4N), grid 512 -> 2 blocks/CU. A via swizzled LDS dbuf with distance-4
// reg ring; W1/W2 register-direct from L2 blob (distance-2 ring). Raw-barrier
// pipeline keeps global prefetches in flight across k-steps.
// ---------------------------------------------------------------------------
__global__ __launch_bounds__(512, 4) void k_mega(
    const float* __restrict__ A,      // content [16384][1024]
    const float* __restrict__ theta,  // [16384][256]
    const float* __restrict__ b1, const float* __restrict__ b2,
    const float* __restrict__ logPi, const float* __restrict__ logR,
    const char* __restrict__ blobs,
    float* __restrict__ out0,         // S
    float* __restrict__ out2,         // K fill
    float* __restrict__ carry)        // out3: slot blk*8192 + c
{
    __shared__ _Float16 Ah[2][32][32];   // swizzled 16B segs, 2048 B / buf
    __shared__ _Float16 Al[2][32][32];
    __shared__ _Float16 Hh[32][136];     // 272 B stride, swizzled segs
    __shared__ _Float16 Hl[32][136];
    __shared__ float    Z[32][260];

    const int tid  = threadIdx.x;
    const int blk  = blockIdx.x;
    const int m0   = blk * CLK;
    const int lane = tid & 63;
    const int wid  = tid >> 6;
    const int ln15 = lane & 15;
    const int q    = lane >> 4;
    const int mh   = wid & 1;    // M half: rows 16*mh..+15
    const int np   = wid >> 1;   // 0..3

    // ---- A staging indices (thread t: row t>>4, 2 elems at k=(t&15)*2)
    const int srow = tid >> 4, skp = (tid & 15) * 2;
    const int ssw  = (srow >> 1) & 3;
    char* ah_w = (char*)&Ah[0][0][0] + srow * 64 + (((skp >> 3) ^ ssw) << 4) + (skp & 7) * 2;
    char* al_w = (char*)&Al[0][0][0] + srow * 64 + (((skp >> 3) ^ ssw) << 4) + (skp & 7) * 2;
    const float* ag = A + (size_t)(m0 + srow) * DM + skp;

    // ---- A-frag read offset (swizzled; 2-way banks = free)
    const int frow  = 16 * mh + ln15;
    const int fsw   = (frow >> 1) & 3;
    const int fq    = q ^ fsw;
    const int abyte = frow * 64 + (fq << 4);

    const char* w1base = blobs + (32 * np + ln15) * 80 + q * 16;

    v4f acc1[2], acc2[2];
    acc1[0] = acc1[1] = (v4f){0.f, 0.f, 0.f, 0.f};
    acc2[0] = acc2[1] = (v4f){0.f, 0.f, 0.f, 0.f};

    // ---- prologue: A ring (distance 4) + W ring (distance 2), stage tile 0
    float2 pa[4];
    #pragma unroll
    for (int j = 0; j < 4; ++j) pa[j] = *(const float2*)(ag + j * 32);
    {
        union { _Float16 h[2]; unsigned u; } ph, pl;
        float x0 = pa[0].x, x1 = pa[0].y;
        _Float16 h0 = (_Float16)x0, h1 = (_Float16)x1;
        ph.h[0] = h0; ph.h[1] = h1;
        pl.h[0] = (_Float16)((x0 - (float)h0) * 4096.f);
        pl.h[1] = (_Float16)((x1 - (float)h1) * 4096.f);
        *(unsigned*)(ah_w) = ph.u;
        *(unsigned*)(al_w) = pl.u;
    }
    pa[0] = *(const float2*)(ag + 4 * 32);

    v8h wh0[2], wh1[2], wl0[2], wl1[2];
    #pragma unroll
    for (int s = 0; s < 2; ++s) {
        const char* wp = w1base + s * W1BLOB_TILE;
        wh0[s] = *(const v8h*)(wp);
        wh1[s] = *(const v8h*)(wp + 1280);
        wl0[s] = *(const v8h*)(wp + 10240);
        wl1[s] = *(const v8h*)(wp + 11520);
    }
    BAR_LGKM();

    // ---- GEMM1 main loop: 32 k-steps, 1 lgkm-barrier each, vmcnt stays hot
    for (int it = 0; it < 8; ++it) {
        #pragma unroll
        for (int j = 0; j < 4; ++j) {
            const int kt  = it * 4 + j;
            const int cur = kt & 1;
            const int ps  = (j + 1) & 3;
            if (kt < 31) {
                // stage tile kt+1 into buf (kt+1)&1 from ring, refill ring +4
                union { _Float16 h[2]; unsigned u; } ph, pl;
                float x0 = pa[ps].x, x1 = pa[ps].y;
                _Float16 h0 = (_Float16)x0, h1 = (_Float16)x1;
                ph.h[0] = h0; ph.h[1] = h1;
                pl.h[0] = (_Float16)((x0 - (float)h0) * 4096.f);
                pl.h[1] = (_Float16)((x1 - (float)h1) * 4096.f);
                *(unsigned*)(ah_w + (cur ^ 1) * 2048) = ph.u;
                *(unsigned*)(al_w + (cur ^ 1) * 2048) = pl.u;
                int kn = kt + 5; if (kn > 31) kn = 31;
                pa[ps] = *(const float2*)(ag + kn * 32);
            }
            v8h ah = *(const v8h*)((const char*)&Ah[0][0][0] + cur * 2048 + abyte);
            v8h al = *(const v8h*)((const char*)&Al[0][0][0] + cur * 2048 + abyte);
            acc1[0] = MFMA16(ah, wh0[cur], acc1[0]);
            acc1[1] = MFMA16(ah, wh1[cur], acc1[1]);
            acc2[0] = MFMA16(ah, wl0[cur], acc2[0]);
            acc2[0] = MFMA16(al, wh0[cur], acc2[0]);
            acc2[1] = MFMA16(ah, wl1[cur], acc2[1]);
            acc2[1] = MFMA16(al, wh1[cur], acc2[1]);
            if (kt < 30) {   // refill W ring slot with tile kt+2
                const char* wp = w1base + (kt + 2) * W1BLOB_TILE;
                wh0[cur] = *(const v8h*)(wp);
                wh1[cur] = *(const v8h*)(wp + 1280);
                wl0[cur] = *(const v8h*)(wp + 10240);
                wl1[cur] = *(const v8h*)(wp + 11520);
            }
            BAR_LGKM();
        }
    }

    // ---- prefetch GEMM2 ks=0 W2 frags (stay in flight across GELU barrier)
    const char* w2base = blobs + W2BLOB_BASE + (64 * np + ln15) * 80 + q * 16;
    v8h w2h0[4], w2l0[4];
    #pragma unroll
    for (int ni = 0; ni < 4; ++ni) {
        w2h0[ni] = *(const v8h*)(w2base + ni * 1280);
        w2l0[ni] = *(const v8h*)(w2base + ni * 1280 + 20480);
    }

    // ---- GELU -> H split into swizzled LDS
    #pragma unroll
    for (int ni = 0; ni < 2; ++ni) {
        const int col = 32 * np + 16 * ni + ln15;
        const float bv = b1[col];
        #pragma unroll
        for (int r = 0; r < 4; ++r) {
            const int row = 16 * mh + 4 * q + r;
            float y = acc1[ni][r] + acc2[ni][r] * (1.f / 4096.f) + bv;
            float h = 0.5f * y * (1.f + erff(y * 0.70710678118654752f));
            _Float16 hh = (_Float16)h;
            _Float16 hl = (_Float16)((h - (float)hh) * 4096.f);
            const int sw = (row >> 1) & 3;
            const int byte = row * 272 + (((col >> 3) ^ sw) << 4) + (col & 7) * 2;
            *(_Float16*)((char*)&Hh[0][0] + byte) = hh;
            *(_Float16*)((char*)&Hl[0][0] + byte) = hl;
        }
    }
    BAR_LGKM();

    // ---- GEMM2: out 32x256, K=128; W2 register-direct
    v4f c1[4], c2[4];
    #pragma unroll
    for (int i = 0; i < 4; ++i) {
        c1[i] = (v4f){0.f, 0.f, 0.f, 0.f};
        c2[i] = (v4f){0.f, 0.f, 0.f, 0.f};
    }
    #pragma unroll
    for (int ks = 0; ks < 4; ++ks) {
        const int hbyte = frow * 272 + ((4 * ks + fq) << 4);
        v8h hh = *(const v8h*)((const char*)&Hh[0][0] + hbyte);
        v8h hl = *(const v8h*)((const char*)&Hl[0][0] + hbyte);
        #pragma unroll
        for (int ni = 0; ni < 4; ++ni) {
            v8h wh, wl;
            if (ks == 0) { wh = w2h0[ni]; wl = w2l0[ni]; }
            else {
                const char* wp = w2base + ks * W2BLOB_TILE + ni * 1280;
                wh = *(const v8h*)(wp);
                wl = *(const v8h*)(wp + 20480);
            }
            c1[ni] = MFMA16(hh, wh, c1[ni]);
            c2[ni] = MFMA16(hh, wl, c2[ni]);
            c2[ni] = MFMA16(hl, wh, c2[ni]);
        }
    }

    // ---- z = pi*tanh(y2) -> LDS
    #pragma unroll
    for (int ni = 0; ni < 4; ++ni) {
        const int col = 64 * np + 16 * ni + ln15;
        const float bv = b2[col];
        #pragma unroll
        for (int r = 0; r < 4; ++r) {
            const int row = 16 * mh + 4 * q + r;
            float y2 = c1[ni][r] + c2[ni][r] * (1.f / 4096.f) + bv;
            Z[row][col] = 3.14159265358979323846f * tanhf(y2);
        }
    }

    // ---- theta batch prefetch (in flight across the barrier)
    float tv[CLK];
    if (tid < 256) {
        #pragma unroll
        for (int i = 0; i < CLK; ++i)
            tv[i] = theta[(size_t)(m0 + i) * HNB + tid];
    }
    BAR_LGKM();

    // ---- wrap + u + in-block scan; S & carry (lower half), K fill (upper)
    if (tid < 256) {
        const int c = tid;
        const float Pi = expf(logPi[c]);
        const float Rr = expf(logR[c]);
        const float Kc = Pi / fmaxf(Pi + Rr, 1e-8f);
        const float alpha = 1.f - Kc;
        float d = 0.f;
        float sv[CLK];
        #pragma unroll
        for (int i = 0; i < CLK; ++i) {
            float diff = Z[i][c] - tv[i];
            float kq = rintf(diff * 0.15915494309189533577f);
            float nu = (float)((double)diff - (double)kq * 6.283185307179586476925286766559);
            d = fmaf(alpha, d, Kc * nu);
            sv[i] = tv[i] + d;
        }
        #pragma unroll
        for (int i = 0; i < CLK; ++i)
            out0[(size_t)(m0 + i) * HNB + c] = sv[i];
        carry[(size_t)blk * 8192 + c] = d;
    } else {
        const int c = tid - 256;
        const float Pi = expf(logPi[c]);
        const float Rr = expf(logR[c]);
        const float Kc = Pi / fmaxf(Pi + Rr, 1e-8f);
        #pragma unroll
        for (int i = 0; i < CLK; ++i)
            out2[(size_t)(m0 + i) * HNB + c] = Kc;
    }
}

// ---------------------------------------------------------------------------
// K2: exclusive scan of chunk carries (factor alpha^32), 4 blocks (one/batch).
// ---------------------------------------------------------------------------
__global__ __launch_bounds__(256) void k_cscan(
    const float* __restrict__ logPi,
    const float* __restrict__ logR,
    float* __restrict__ carry)
{
    const int c = threadIdx.x;
    const int b = blockIdx.x;
    const float Pi = expf(logPi[c]);
    const float Rr = expf(logR[c]);
    const float alpha = 1.f - Pi / fmaxf(Pi + Rr, 1e-8f);
    float A32 = alpha;
    #pragma unroll
    for (int i = 0; i < 5; ++i) A32 = A32 * A32;   // alpha^32
    float D = 0.f;
    for (int s0 = 0; s0 < CPB; s0 += 16) {
        float a[16];
        #pragma unroll
        for (int j = 0; j < 16; ++j)
            a[j] = carry[(size_t)(b * CPB + s0 + j) * 8192 + c];
        #pragma unroll
        for (int j = 0; j < 16; ++j) {
            carry[(size_t)(b * CPB + s0 + j) * 8192 + c] = D;
            D = fmaf(A32, D, a[j]);
        }
    }
}

// ---------------------------------------------------------------------------
// K3: out0 += alpha^(i+1)*D; fill Pi (out1), R (out3). One block per chunk;
//     D read-before-fill from the chunk's own out3 region.
// ---------------------------------------------------------------------------
__global__ __launch_bounds__(256) void k_apply_fill(
    const float* __restrict__ logPi,
    const float* __restrict__ logR,
    float* __restrict__ out0, float* __restrict__ out1,
    float* __restrict__ out3)
{
    const int blk = blockIdx.x;
    const int c = threadIdx.x;
    const float Pi = expf(logPi[c]);
    const float Rr = expf(logR[c]);
    const float Kc = Pi / fmaxf(Pi + Rr, 1e-8f);
    const float alpha = 1.f - Kc;
    const size_t base = (size_t)blk * 8192 + c;
    float D = out3[base];
    float w = alpha * D;
    #pragma unroll 4
    for (int i = 0; i < CLK; ++i) {
        size_t idx = base + (size_t)i * 256;
        out0[idx] += w;
        out1[idx] = Pi;
        out3[idx] = Rr;
        w *= alpha;
    }
}

extern "C" void kernel_launch(void* const* d_in, const int* in_sizes, int n_in,
                              void* d_out, int out_size, void* d_ws, size_t ws_size,
                              hipStream_t stream) {
    const float* theta   = (const float*)d_in[0];
    const float* content = (const float*)d_in[1];
    const float* W1      = (const float*)d_in[2];
    const float* b1      = (const float*)d_in[3];
    const float* W2      = (const float*)d_in[4];
    const float* b2      = (const float*)d_in[5];
    const float* logPi   = (const float*)d_in[6];
    const float* logR    = (const float*)d_in[7];

    float* out  = (float*)d_out;
    float* out0 = out;
    float* out1 = out + (size_t)MTOT * HNB;
    float* out2 = out + (size_t)2 * MTOT * HNB;
    float* out3 = out + (size_t)3 * MTOT * HNB;
    char*  blobs = (char*)out1;   // weight blobs until k_apply_fill fills out1

    hipLaunchKernelGGL(k_prep, dim3(36), dim3(256), 0, stream, W1, W2, blobs);
    hipLaunchKernelGGL(k_mega, dim3(NBLK), dim3(512), 0, stream,
                       content, theta, b1, b2, logPi, logR, blobs,
                       out0, out2, out3);
    hipLaunchKernelGGL(k_cscan, dim3(NBAT), dim3(256), 0, stream,
                       logPi, logR, out3);
    hipLaunchKernelGGL(k_apply_fill, dim3(NBLK), dim3(256), 0, stream,
                       logPi, logR, out0, out1, out3);
}